// Round 9
// baseline (584.665 us; speedup 1.0000x reference)
//
#include <hip/hip_runtime.h>
#include <cstddef>

// LSTM T=2048, B=2048, I=1, H=20; gates [f,i,o,c] rows of W/U.
// Round-9: NO LDS, NO barriers, NO DS ops. h broadcast via v_readlane ->
// SGPR (wave-uniform), which forces one batch-set per wave; two batches are
// packed into the f2 element lanes of every operand so the wave count is
// 1024 = exactly 1 wave/SIMD (no issue contention, unlike r8's 2/SIMD).
//  - lane = 2j+p: p=0 computes gates (f,i), p=1 (o,c), for BOTH batches
//    (f2 = (batchA, batchB)). j>=20 lanes are harmless clones.
//  - dot: 40 v_pk_fma_f32 with SGPR-broadcast h (2-way tree split).
//  - r8-proven act algebra: acts = rcp(1+exp2(z)) with pre-scaled weights,
//    per-lane affine fixup, DPP quad_perm pair exchange, c scaled by 2log2e.
//  - x: lane (tid&15) holds step s of the current 16-step chunk (f2 over the
//    2 batches, one dwordx2 load); per-step readlane with compile-time index;
//    chunks prefetched 2 ahead (off-chain vmcnt strand, ~16 steps of slack).

constexpr int T = 2048;
constexpr int B = 2048;
constexpr int H = 20;
constexpr int CHUNK = 16;
constexpr int NCH = T / CHUNK;      // 128 exact

typedef float f2 __attribute__((ext_vector_type(2)));

__device__ __forceinline__ float rcp_f(float v) { return __builtin_amdgcn_rcpf(v); }
__device__ __forceinline__ float ex2(float v)   { return __builtin_amdgcn_exp2f(v); }
__device__ __forceinline__ float rdl(float v, int l) {
  return __int_as_float(__builtin_amdgcn_readlane(__float_as_int(v), l));
}
// quad_perm [1,0,3,2]: swap adjacent even/odd lanes (pair exchange).
__device__ __forceinline__ float dppswap(float v) {
  return __int_as_float(__builtin_amdgcn_update_dpp(
      0, __float_as_int(v), 0xB1, 0xF, 0xF, true));
}

__global__ __launch_bounds__(64, 1)
void lstm_rl(const float* __restrict__ xg, const float* __restrict__ Wg,
             const float* __restrict__ Ug, const float* __restrict__ bwg,
             const float* __restrict__ bug, float* __restrict__ out) {
  const int tid = threadIdx.x;
  const int p   = tid & 1;          // 0 -> gates (f,i), 1 -> gates (o,c)
  const int jr  = tid >> 1;         // 0..31 (20..31 = clone lanes)
  const int jc  = (jr < H) ? jr : (H - 1);
  const int bA  = blockIdx.x * 2;   // two batches per wave (packed in f2)
  const bool st = (p == 0) && (jr < H);

  constexpr float K1 = 1.44269504f; // log2(e)
  const float s0 = -K1;                      // f | o scale
  const float s1 = p ? (2.f * K1) : -K1;     // c -> +2log2e, i -> -log2e
  const int g0 = p ? 2 : 0;
  const int g1 = p ? 3 : 1;

  // Weights duplicated into both f2 halves (same U for both batches).
  f2 u0[H], u1[H];
#pragma unroll
  for (int k = 0; k < H; ++k) {
    const float a = Ug[(g0 * H + jc) * H + k] * s0;
    const float b = Ug[(g1 * H + jc) * H + k] * s1;
    u0[k].x = a; u0[k].y = a;
    u1[k].x = b; u1[k].y = b;
  }
  f2 w0, w1, bb0, bb1, A1d, B1d;
  { const float a = Wg[g0 * H + jc] * s0;                 w0.x = a;  w0.y = a;  }
  { const float a = Wg[g1 * H + jc] * s1;                 w1.x = a;  w1.y = a;  }
  { const float a = (bwg[g0*H+jc] + bug[g0*H+jc]) * s0;   bb0.x = a; bb0.y = a; }
  { const float a = (bwg[g1*H+jc] + bug[g1*H+jc]) * s1;   bb1.x = a; bb1.y = a; }
  // act1 = A1*r + B1: p=0 -> 2K1*sigmoid(i); p=1 -> tanh(g).
  { const float a = p ? -2.f : (2.f * K1);                A1d.x = a; A1d.y = a; }
  { const float a = p ? 1.f : 0.f;                        B1d.x = a; B1d.y = a; }

  // x chunk staging: lane (tid&15) holds step t0+(tid&15), f2 over (bA,bA+1).
  const int sl = tid & 15;
  auto ldx = [&](int t) -> f2 {
    t = (t < T) ? t : (T - 1);                // clamped (harmless over-read)
    return *reinterpret_cast<const f2*>(&xg[(size_t)t * B + bA]);
  };
  f2 xc0 = ldx(sl);                           // chunk 0
  f2 xc1 = ldx(CHUNK + sl);                   // chunk 1

  f2 c2; c2.x = 0.f; c2.y = 0.f;              // c scaled by 2*log2e
  f2 hn; hn.x = 0.f; hn.y = 0.f;

  constexpr size_t OS = (size_t)B * H;
  float* outA = out + (size_t)bA * H + jr;    // only dereferenced when st
  float* outB = outA + H;                     // batch bA+1 row

#define STEP(SS, XC)                                                         \
  {                                                                          \
    /* h broadcast: 40 readlanes -> wave-uniform (SGPR) values. */           \
    f2 hk[H];                                                                \
    _Pragma("unroll")                                                        \
    for (int k = 0; k < H; ++k) {                                            \
      hk[k].x = rdl(hn.x, 2 * k);                                            \
      hk[k].y = rdl(hn.y, 2 * k);                                            \
    }                                                                        \
    f2 xx;                                                                   \
    xx.x = rdl(XC.x, (SS));                                                  \
    xx.y = rdl(XC.y, (SS));                                                  \
    /* 2-way tree-split packed dot: 40 pk_fma total. */                      \
    f2 q0a = bb0, q1a = bb1;                                                 \
    f2 q0b = u0[10] * hk[10], q1b = u1[10] * hk[10];                         \
    _Pragma("unroll")                                                        \
    for (int k = 0; k < 10; ++k) {                                           \
      q0a = u0[k] * hk[k] + q0a;                                             \
      q1a = u1[k] * hk[k] + q1a;                                             \
    }                                                                        \
    _Pragma("unroll")                                                        \
    for (int k = 11; k < H; ++k) {                                           \
      q0b = u0[k] * hk[k] + q0b;                                             \
      q1b = u1[k] * hk[k] + q1b;                                             \
    }                                                                        \
    const f2 z0 = w0 * xx + (q0a + q0b);                                     \
    const f2 z1 = w1 * xx + (q1a + q1b);                                     \
    /* stage-1 acts: shared rcp(1+exp2(z)) + per-lane affine fixup. */       \
    f2 r0, r1;                                                               \
    r0.x = rcp_f(1.f + ex2(z0.x));  r0.y = rcp_f(1.f + ex2(z0.y));           \
    r1.x = rcp_f(1.f + ex2(z1.x));  r1.y = rcp_f(1.f + ex2(z1.y));           \
    const f2 act0 = r0;                       /* sig(f) | sig(o) */          \
    const f2 act1 = A1d * r1 + B1d;           /* 2K1*sig(i) | tanh(g) */     \
    f2 oth0, oth1;                                                           \
    oth0.x = dppswap(act0.x); oth0.y = dppswap(act0.y);                      \
    oth1.x = dppswap(act1.x); oth1.y = dppswap(act1.y);                      \
    f2 fg, og;                                                               \
    fg.x = p ? oth0.x : act0.x;  fg.y = p ? oth0.y : act0.y;                 \
    og.x = p ? act0.x : oth0.x;  og.y = p ? act0.y : oth0.y;                 \
    const f2 igt = act1 * oth1;               /* (2K1*ig)*gt, symmetric */   \
    c2 = fg * c2 + igt;                                                      \
    /* stage-2: tanh(c) = 1 - 2*rcp(1+exp2(2K1*c)). */                       \
    f2 r2;                                                                   \
    r2.x = rcp_f(1.f + ex2(c2.x)); r2.y = rcp_f(1.f + ex2(c2.y));            \
    const f2 tc = r2 * -2.f + 1.f;                                           \
    hn = og * tc;                                                            \
    if (st) { *outA = hn.x; *outB = hn.y; }                                  \
    outA += OS; outB += OS;                                                  \
  }

  for (int ch = 0; ch < NCH; ch += 2) {
    // Prefetch chunk ch+2 (consumed 16 steps later; off-chain vmcnt strand).
    f2 nx0 = ldx((ch + 2) * CHUNK + sl);
#pragma unroll
    for (int s = 0; s < CHUNK; ++s) STEP(s, xc0)
    xc0 = nx0;
    f2 nx1 = ldx((ch + 3) * CHUNK + sl);
#pragma unroll
    for (int s = 0; s < CHUNK; ++s) STEP(s, xc1)
    xc1 = nx1;
  }
#undef STEP

  if (st) {
    out[OS * T + (size_t)bA * H + jr]           = hn.x;                 // h_last A
    out[OS * T + (size_t)bA * H + H + jr]       = hn.y;                 // h_last B
    out[OS * (T + 1) + (size_t)bA * H + jr]     = c2.x * 0.34657359f;   // c_last A
    out[OS * (T + 1) + (size_t)bA * H + H + jr] = c2.y * 0.34657359f;   // c_last B
  }
}

extern "C" void kernel_launch(void* const* d_in, const int* in_sizes, int n_in,
                              void* d_out, int out_size, void* d_ws, size_t ws_size,
                              hipStream_t stream) {
  (void)in_sizes; (void)n_in; (void)d_ws; (void)ws_size; (void)out_size;
  const float* x  = (const float*)d_in[0];
  const float* W  = (const float*)d_in[1];
  const float* U  = (const float*)d_in[2];
  const float* bw = (const float*)d_in[3];
  const float* bu = (const float*)d_in[4];
  float* out = (float*)d_out;

  lstm_rl<<<dim3(B / 2), dim3(64), 0, stream>>>(x, W, U, bw, bu, out);
}

// Round 10
// 497.001 us; speedup vs baseline: 1.1764x; 1.1764x over previous
//
#include <hip/hip_runtime.h>
#include <cstddef>
#include <cstdint>

// LSTM T=2048, B=2048, I=1, H=20; gates [f,i,o,c] rows of W/U.
// Wall = T x single-wave per-step chain L (latency-bound recurrence).
// Round-10: r4 structure with an ASM-PINNED exchange to remove compiler
// waitcnt slop:
//  - single h buffer; per step ONE volatile asm cluster:
//      5x ds_read_b128 (h row) + ds_read_b32 (x) + s_waitcnt lgkmcnt(0)
//    then sched_barrier(0)  [rule #18], compute, volatile ds_write_b32.
//    Write->read ordering relies on the per-wave in-order DS FIFO (reads of
//    step s+1 issue right after the write of step s, no drain between).
//  - all LDS ops in the loop are volatile asm => program order = issue order;
//    the r3-class compiler reorder is structurally impossible.
//  - x staged in LDS per 16-step chunk (writes via asm ds_write), prefetched
//    one chunk ahead in registers (vmcnt strand off the chain).
//  - split-4 packed dot (r8-proven), pre-scaled weights, c scaled by 2log2e.

constexpr int T = 2048;
constexpr int B = 2048;
constexpr int H = 20;
constexpr int GR = 3;               // batch groups per wave (lanes 0..59)
constexpr int SLOTS = 4;            // 3 real + 1 dummy group
constexpr int ROW = 36;             // floats per h row: 144 B, 16B-aligned
constexpr int CHUNK = 16;
constexpr int NCH = T / CHUNK;      // 128 exact

typedef float f2 __attribute__((ext_vector_type(2)));
typedef float f4 __attribute__((ext_vector_type(4)));

__device__ __forceinline__ float rcp_f(float v) { return __builtin_amdgcn_rcpf(v); }
__device__ __forceinline__ float ex2(float v)   { return __builtin_amdgcn_exp2f(v); }

__global__ __launch_bounds__(64, 1)
void lstm_w10(const float* __restrict__ xg, const float* __restrict__ Wg,
              const float* __restrict__ Ug, const float* __restrict__ bwg,
              const float* __restrict__ bug, float* __restrict__ out) {
  __shared__ __align__(16) float hx[SLOTS * ROW];        // h exchange (576 B)
  __shared__ __align__(16) float xl[2 * SLOTS * CHUNK];  // x staging (512 B)

  const int tid = threadIdx.x;
  const int bl  = tid / H;                    // 0..3 (3 = dummy group)
  const int j   = tid % H;                    // hidden unit
  const int bg0 = blockIdx.x * GR + bl;
  const bool st = (bl < GR) && (bg0 < B);
  const int bgi = (bg0 < B) ? bg0 : (B - 1);  // clamped batch for loads

  constexpr float K1 = 1.44269504f;           // log2(e)

  // Packed pre-scaled weights: (f,i) * -log2e ; (o) * -log2e, (c) * +2log2e.
  f2 u01[H], u23[H], w01, w23, b01, b23;
#pragma unroll
  for (int k = 0; k < H; ++k) {
    u01[k].x = Ug[(0 * H + j) * H + k] * (-K1);
    u01[k].y = Ug[(1 * H + j) * H + k] * (-K1);
    u23[k].x = Ug[(2 * H + j) * H + k] * (-K1);
    u23[k].y = Ug[(3 * H + j) * H + k] * (2.0f * K1);
  }
  w01.x = Wg[0 * H + j] * (-K1);   w01.y = Wg[1 * H + j] * (-K1);
  w23.x = Wg[2 * H + j] * (-K1);   w23.y = Wg[3 * H + j] * (2.0f * K1);
  b01.x = (bwg[0 * H + j] + bug[0 * H + j]) * (-K1);
  b01.y = (bwg[1 * H + j] + bug[1 * H + j]) * (-K1);
  b23.x = (bwg[2 * H + j] + bug[2 * H + j]) * (-K1);
  b23.y = (bwg[3 * H + j] + bug[3 * H + j]) * (2.0f * K1);

  // LDS byte offsets (generic LDS address low 32 bits = DS offset).
  const uint32_t hrd = (uint32_t)(size_t)(&hx[bl * ROW]);       // read base
  const uint32_t hwr = hrd + 4u * (uint32_t)j;                  // write slot
  const uint32_t xb  = (uint32_t)(size_t)(&xl[0]) + 64u * (uint32_t)bl;
  const uint32_t xwb = (uint32_t)(size_t)(&xl[0]) + 64u * (uint32_t)bl
                       + 4u * (uint32_t)j;                      // j<16 only

  // Deterministic zero-init; stage x chunk 0; prefetch chunk 1 (registers).
  for (int q = tid; q < SLOTS * ROW; q += 64) hx[q] = 0.f;
  for (int q = tid; q < 2 * SLOTS * CHUNK; q += 64) xl[q] = 0.f;
  if (j < CHUNK) xl[0 * 64 + bl * 16 + j] = xg[(size_t)j * B + bgi];
  float xnext = (j < CHUNK) ? xg[(size_t)(CHUNK + j) * B + bgi] : 0.f;
  // Fence: pin all init stores before the first asm read (order + completion).
  asm volatile("s_waitcnt lgkmcnt(0)" ::: "memory");

  float c2 = 0.f, hn = 0.f;                   // c scaled by 2*log2e
  float* outp = out + (size_t)bgi * H + j;
  constexpr size_t OS = (size_t)B * H;

  for (int ch = 0; ch < NCH; ++ch) {
    const int cb = ch & 1;
    const uint32_t xrd = xb + (uint32_t)(cb * 256);
    // Stage chunk ch+1 (held in xnext) via asm ds_write; prefetch ch+2.
    if (j < CHUNK) {
      const uint32_t xw = xwb + (uint32_t)((cb ^ 1) * 256);
      asm volatile("ds_write_b32 %0, %1" :: "v"(xw), "v"(xnext));
      const int tp = (ch + 2) * CHUNK + j;
      xnext = (tp < T) ? xg[(size_t)tp * B + bgi] : 0.f;
    }
#pragma unroll
    for (int s = 0; s < CHUNK; ++s) {
      f4 v0, v1, v2, v3, v4; float xvv;
      asm volatile(
        "ds_read_b128 %0, %6 offset:0\n\t"
        "ds_read_b128 %1, %6 offset:16\n\t"
        "ds_read_b128 %2, %6 offset:32\n\t"
        "ds_read_b128 %3, %6 offset:48\n\t"
        "ds_read_b128 %4, %6 offset:64\n\t"
        "ds_read_b32  %5, %7 offset:%8\n\t"
        "s_waitcnt lgkmcnt(0)"
        : "=v"(v0), "=v"(v1), "=v"(v2), "=v"(v3), "=v"(v4), "=v"(xvv)
        : "v"(hrd), "v"(xrd), "i"(4 * s));
      __builtin_amdgcn_sched_barrier(0);      // rule #18: no hoist past wait
      const float hb[H] = {v0.x, v0.y, v0.z, v0.w, v1.x, v1.y, v1.z, v1.w,
                           v2.x, v2.y, v2.z, v2.w, v3.x, v3.y, v3.z, v3.w,
                           v4.x, v4.y, v4.z, v4.w};
      // Split-4 packed dots (depth 5 + 2 combine levels).
      f2 qa01 = b01, qa23 = b23;
      f2 h5;  h5.x  = hb[5];  h5.y  = hb[5];
      f2 h10; h10.x = hb[10]; h10.y = hb[10];
      f2 h15; h15.x = hb[15]; h15.y = hb[15];
      f2 qb01 = u01[5]  * h5,  qb23 = u23[5]  * h5;
      f2 qc01 = u01[10] * h10, qc23 = u23[10] * h10;
      f2 qd01 = u01[15] * h15, qd23 = u23[15] * h15;
#pragma unroll
      for (int k = 0; k < 5; ++k)   { f2 hk; hk.x = hb[k]; hk.y = hb[k];
                                      qa01 = u01[k] * hk + qa01;
                                      qa23 = u23[k] * hk + qa23; }
#pragma unroll
      for (int k = 6; k < 10; ++k)  { f2 hk; hk.x = hb[k]; hk.y = hb[k];
                                      qb01 = u01[k] * hk + qb01;
                                      qb23 = u23[k] * hk + qb23; }
#pragma unroll
      for (int k = 11; k < 15; ++k) { f2 hk; hk.x = hb[k]; hk.y = hb[k];
                                      qc01 = u01[k] * hk + qc01;
                                      qc23 = u23[k] * hk + qc23; }
#pragma unroll
      for (int k = 16; k < 20; ++k) { f2 hk; hk.x = hb[k]; hk.y = hb[k];
                                      qd01 = u01[k] * hk + qd01;
                                      qd23 = u23[k] * hk + qd23; }
      f2 xv2; xv2.x = xvv; xv2.y = xvv;
      const f2 z01 = w01 * xv2 + ((qa01 + qb01) + (qc01 + qd01));
      const f2 z23 = w23 * xv2 + ((qa23 + qb23) + (qc23 + qd23));
      // Activations (pre-scaled: no muls on the serial chain).
      const float fg = rcp_f(1.f + ex2(z01.x));                  // sigmoid f
      const float ig = rcp_f(1.f + ex2(z01.y));                  // sigmoid i
      const float og = rcp_f(1.f + ex2(z23.x));                  // sigmoid o
      const float gt = fmaf(-2.f, rcp_f(1.f + ex2(z23.y)), 1.f); // tanh g
      const float igt2 = (2.f * K1 * ig) * gt;  // parallel to fg chain
      c2 = fmaf(fg, c2, igt2);                  // c scaled by 2log2e
      const float r2 = rcp_f(1.f + ex2(c2));    // tanh(c) = 1 - 2*r2
      hn = fmaf(-2.f * og, r2, og);
      // Exchange write: in-order DS FIFO makes next step's reads safe.
      asm volatile("ds_write_b32 %0, %1" :: "v"(hwr), "v"(hn));
      if (st) *outp = hn;
      outp += OS;
    }
  }

  if (st) {
    out[OS * T + (size_t)bg0 * H + j] = hn;                       // h_last
    out[OS * (T + 1) + (size_t)bg0 * H + j] = c2 * 0.34657359f;   // c_last
  }
}

extern "C" void kernel_launch(void* const* d_in, const int* in_sizes, int n_in,
                              void* d_out, int out_size, void* d_ws, size_t ws_size,
                              hipStream_t stream) {
  (void)in_sizes; (void)n_in; (void)d_ws; (void)ws_size; (void)out_size;
  const float* x  = (const float*)d_in[0];
  const float* W  = (const float*)d_in[1];
  const float* U  = (const float*)d_in[2];
  const float* bw = (const float*)d_in[3];
  const float* bu = (const float*)d_in[4];
  float* out = (float*)d_out;

  const int grid = (B + GR - 1) / GR;         // 683 one-wave blocks
  lstm_w10<<<dim3(grid), dim3(64), 0, stream>>>(x, W, U, bw, bu, out);
}